// Round 3
// baseline (127.418 us; speedup 1.0000x reference)
//
#include <hip/hip_runtime.h>
#include <hip/hip_bf16.h>

// out[b,k] = sum_{i,j} x[b,i] * W[k,i,j] * x[b,j]
// GEMM P (B x 136 sym-pairs) @ Q (136 x 16), K padded to 160 = 5 x mfma_f32_16x16x32_bf16.
//
// Divergence-free A-frag build (see R2): lane quad q loads its row ROTATED by 4q
// (chunk u <- raw chunk (u+q)&3); pair->K-slot permutation chosen so slot class
// c (= 8s+j) at quad q holds pair ((alpha_c+4q)%16, (beta_c+4q)%16). All lanes run
// identical code with compile-time pair indices.
//
// R3 changes (latency-bound at 44.7us, all pipes <40%):
//  - 4 tiles per wave-iteration: all 12 global_load_dwordx4 issued before any
//    compute -> 4x outstanding bytes per wave (MLP), amortized vmcnt waits.
//  - Q built once by a 1-block pre-kernel into d_ws; main kernel loads B-frags
//    from global (L2-hot) -> no LDS, no __syncthreads, cheaper block startup.

typedef __attribute__((ext_vector_type(8)))  short  short8;
typedef __attribute__((ext_vector_type(8)))  __bf16 bf16x8;
typedef __attribute__((ext_vector_type(4)))  float  floatx4;

#define DEV static __device__ __forceinline__

constexpr int  alpha_of(int c) { return (c < 32) ? (c & 3) : (c - 32); }
constexpr int  beta_of(int c)  { return (c < 32) ? ((c & 3) + (c >> 2)) : (c - 32 + 8); }
constexpr bool live_of(int c)  { return c < 36; }

template <int C>
DEV float pval(const float* xv) {
    if constexpr (!live_of(C)) return 0.f;
    else return xv[alpha_of(C)] * xv[beta_of(C)];   // constant indices, uniform code
}

template <int S>   // frag S covers classes c = 8S .. 8S+7
DEV short8 make_afrag(const float* xv) {
    union { short8 s; __hip_bfloat162 h[4]; } u;
    u.h[0] = __float22bfloat162_rn(make_float2(pval<8 * S + 0>(xv), pval<8 * S + 1>(xv)));
    u.h[1] = __float22bfloat162_rn(make_float2(pval<8 * S + 2>(xv), pval<8 * S + 3>(xv)));
    u.h[2] = __float22bfloat162_rn(make_float2(pval<8 * S + 4>(xv), pval<8 * S + 5>(xv)));
    u.h[3] = __float22bfloat162_rn(make_float2(pval<8 * S + 6>(xv), pval<8 * S + 7>(xv)));
    return u.s;
}

DEV floatx4 mfma_bf16(short8 a, short8 b, floatx4 c) {
    return __builtin_amdgcn_mfma_f32_16x16x32_bf16(
        __builtin_bit_cast(bf16x8, a), __builtin_bit_cast(bf16x8, b), c, 0, 0, 0);
}

// ---- Q element for flat slot index e (= n*160 + k), shared by both setup paths ----
DEV float q_elem(const float* __restrict__ W, int e) {
    const int n = e / 160;
    const int k = e - n * 160;
    const int s = k >> 5, q = (k >> 3) & 3, j = k & 7;
    const int c = 8 * s + j;
    float qv = 0.f;
    if (c < 36) {
        const int a = (c < 32) ? (c & 3) : (c - 32);
        const int b = (c < 32) ? ((c & 3) + (c >> 2)) : (c - 32 + 8);
        const float w = (c < 32) ? 1.0f : 0.5f;
        const int I = (a + 4 * q) & 15, J = (b + 4 * q) & 15;
        qv = (I == J) ? W[n * 256 + I * 16 + I]
                      : w * (W[n * 256 + I * 16 + J] + W[n * 256 + J * 16 + I]);
    }
    return qv;
}

__global__ void qprep_kernel(const float* __restrict__ W, short* __restrict__ Qg) {
    for (int e = threadIdx.x; e < 16 * 160; e += 256) {
        __hip_bfloat16 h = __float2bfloat16(q_elem(W, e));
        Qg[e] = *reinterpret_cast<short*>(&h);
    }
}

// ---- one 16x16 tile: 3 rotated chunks -> 5 A-frags -> 5 MFMA -> 4 stores ----
DEV void do_tile(const float4 c0, const float4 c1, const float4 c2,
                 const short8 b0, const short8 b1, const short8 b2,
                 const short8 b3, const short8 b4, float* __restrict__ ob) {
    const float xv[12] = {c0.x, c0.y, c0.z, c0.w,
                          c1.x, c1.y, c1.z, c1.w,
                          c2.x, c2.y, c2.z, c2.w};
    floatx4 acc = {0.f, 0.f, 0.f, 0.f};
    acc = mfma_bf16(make_afrag<0>(xv), b0, acc);
    acc = mfma_bf16(make_afrag<1>(xv), b1, acc);
    acc = mfma_bf16(make_afrag<2>(xv), b2, acc);
    acc = mfma_bf16(make_afrag<3>(xv), b3, acc);
    acc = mfma_bf16(make_afrag<4>(xv), b4, acc);
    // C/D layout: col = lane&15, row = quad*4 + reg  [m89-verified]
    ob[0]  = acc[0];
    ob[16] = acc[1];
    ob[32] = acc[2];
    ob[48] = acc[3];
}

__global__ __launch_bounds__(256, 4)
void bilinear16_main(const float* __restrict__ x, const short* __restrict__ Qg,
                     float* __restrict__ out, int nbatch) {   // nbatch = groups of 4 tiles
    const int tid  = threadIdx.x;
    const int lane = tid & 63;
    const int n    = lane & 15;   // A row m / B col n / C col
    const int q    = lane >> 4;   // quad -> data rotation only, never a branch

    // B-frags from global (5 KB, L2-hot after qprep) — live in registers all loop.
    const short8 b0 = *reinterpret_cast<const short8*>(Qg + n * 160 + 0 * 32 + q * 8);
    const short8 b1 = *reinterpret_cast<const short8*>(Qg + n * 160 + 1 * 32 + q * 8);
    const short8 b2 = *reinterpret_cast<const short8*>(Qg + n * 160 + 2 * 32 + q * 8);
    const short8 b3 = *reinterpret_cast<const short8*>(Qg + n * 160 + 3 * 32 + q * 8);
    const short8 b4 = *reinterpret_cast<const short8*>(Qg + n * 160 + 4 * 32 + q * 8);

    const int waveId = blockIdx.x * 4 + (tid >> 6);
    const int nwaves = gridDim.x * 4;

    for (int g = waveId; g < nbatch; g += nwaves) {
        const size_t t0 = (size_t)g * 4;          // 4 contiguous tiles per iteration
        // Rotated chunk bases: rotated chunk u = raw chunk (u+q)&3 of row n.
        // Each load inst's 64 lanes cover one full 1KB tile (dense, minimal lines).
        const float4* xA = reinterpret_cast<const float4*>(x + t0 * 256) + n * 4;
        const float4* A0 = xA + ((q + 0) & 3);
        const float4* A1 = xA + ((q + 1) & 3);
        const float4* A2 = xA + ((q + 2) & 3);

        // All 12 loads in flight before any compute (tile stride = 64 float4s).
        const float4 c00 = A0[0],   c01 = A1[0],   c02 = A2[0];
        const float4 c10 = A0[64],  c11 = A1[64],  c12 = A2[64];
        const float4 c20 = A0[128], c21 = A1[128], c22 = A2[128];
        const float4 c30 = A0[192], c31 = A1[192], c32 = A2[192];

        float* ob = out + t0 * 256 + q * 64 + n;
        do_tile(c00, c01, c02, b0, b1, b2, b3, b4, ob);
        do_tile(c10, c11, c12, b0, b1, b2, b3, b4, ob + 256);
        do_tile(c20, c21, c22, b0, b1, b2, b3, b4, ob + 512);
        do_tile(c30, c31, c32, b0, b1, b2, b3, b4, ob + 768);
    }
}

// ---- fallback (ws too small): R2 single-kernel LDS path ----
__global__ __launch_bounds__(256, 4)
void bilinear16_lds(const float* __restrict__ x, const float* __restrict__ W,
                    float* __restrict__ out, int ntiles) {
    __shared__ __align__(16) short Qt[16][160];
    const int tid = threadIdx.x;
    for (int e = tid; e < 16 * 160; e += 256) {
        __hip_bfloat16 h = __float2bfloat16(q_elem(W, e));
        Qt[0][e] = *reinterpret_cast<short*>(&h);
    }
    __syncthreads();

    const int lane = tid & 63;
    const int n    = lane & 15;
    const int q    = lane >> 4;

    const short8 b0 = *reinterpret_cast<const short8*>(&Qt[n][0 * 32 + q * 8]);
    const short8 b1 = *reinterpret_cast<const short8*>(&Qt[n][1 * 32 + q * 8]);
    const short8 b2 = *reinterpret_cast<const short8*>(&Qt[n][2 * 32 + q * 8]);
    const short8 b3 = *reinterpret_cast<const short8*>(&Qt[n][3 * 32 + q * 8]);
    const short8 b4 = *reinterpret_cast<const short8*>(&Qt[n][4 * 32 + q * 8]);

    const int waveId = blockIdx.x * 4 + (tid >> 6);
    const int nwaves = gridDim.x * 4;

    for (int t = waveId; t < ntiles; t += nwaves) {
        const float4* xr = reinterpret_cast<const float4*>(x + (size_t)(t * 16 + n) * 16);
        const float4 c0 = xr[q];
        const float4 c1 = xr[(q + 1) & 3];
        const float4 c2 = xr[(q + 2) & 3];
        float* ob = out + (size_t)t * 256 + q * 64 + n;
        do_tile(c0, c1, c2, b0, b1, b2, b3, b4, ob);
    }
}

extern "C" void kernel_launch(void* const* d_in, const int* in_sizes, int n_in,
                              void* d_out, int out_size, void* d_ws, size_t ws_size,
                              hipStream_t stream) {
    const float* x = (const float*)d_in[0];
    const float* W = (const float*)d_in[1];
    float* out = (float*)d_out;
    const int Bn = in_sizes[0] / 16;   // 1048576
    const int ntiles = Bn >> 4;        // 65536

    if (ws_size >= (size_t)(16 * 160 * sizeof(short))) {
        short* Qg = (short*)d_ws;
        qprep_kernel<<<1, 256, 0, stream>>>(W, Qg);
        const int nbatch = (ntiles + 3) >> 2;     // 16384 groups of 4 tiles
        bilinear16_main<<<2048, 256, 0, stream>>>(x, Qg, out, nbatch);
    } else {
        bilinear16_lds<<<2048, 256, 0, stream>>>(x, W, out, ntiles);
    }
}

// Round 4
// 126.455 us; speedup vs baseline: 1.0076x; 1.0076x over previous
//
#include <hip/hip_runtime.h>
#include <hip/hip_bf16.h>

// out[b,k] = sum_{i,j} x[b,i] * W[k,i,j] * x[b,j]
// GEMM P (B x 136 sym-pairs) @ Q (136 x 16), K padded to 160 = 5 x mfma_f32_16x16x32_bf16.
//
// Divergence-free A-frag build (see R2): lane quad q loads its row ROTATED by 4q
// (chunk u <- raw chunk (u+q)&3); the pair->K-slot permutation is chosen so slot
// class c (= 8s+j) at quad q holds pair ((alpha_c+4q)%16, (beta_c+4q)%16). All
// lanes run identical code with compile-time pair indices.
//
// R4: occupancy was the limiter, not per-wave MLP (R3's 4x batching was neutral).
// __launch_bounds__(256,4) capped us at 16 waves/CU; this kernel needs only
// ~36 VGPRs, so (256,8) doubles resident waves (target 32/CU). Single kernel
// again (no serialized qprep launch); Q built in LDS per block.

typedef __attribute__((ext_vector_type(8)))  short  short8;
typedef __attribute__((ext_vector_type(8)))  __bf16 bf16x8;
typedef __attribute__((ext_vector_type(4)))  float  floatx4;

#define DEV static __device__ __forceinline__

constexpr int  alpha_of(int c) { return (c < 32) ? (c & 3) : (c - 32); }
constexpr int  beta_of(int c)  { return (c < 32) ? ((c & 3) + (c >> 2)) : (c - 32 + 8); }
constexpr bool live_of(int c)  { return c < 36; }

template <int C>
DEV float pval(const float* xv) {
    if constexpr (!live_of(C)) return 0.f;
    else return xv[alpha_of(C)] * xv[beta_of(C)];   // constant indices, uniform code
}

template <int S>   // frag S covers classes c = 8S .. 8S+7
DEV short8 make_afrag(const float* xv) {
    union { short8 s; __hip_bfloat162 h[4]; } u;
    u.h[0] = __float22bfloat162_rn(make_float2(pval<8 * S + 0>(xv), pval<8 * S + 1>(xv)));
    u.h[1] = __float22bfloat162_rn(make_float2(pval<8 * S + 2>(xv), pval<8 * S + 3>(xv)));
    u.h[2] = __float22bfloat162_rn(make_float2(pval<8 * S + 4>(xv), pval<8 * S + 5>(xv)));
    u.h[3] = __float22bfloat162_rn(make_float2(pval<8 * S + 6>(xv), pval<8 * S + 7>(xv)));
    return u.s;
}

DEV floatx4 mfma_bf16(short8 a, short8 b, floatx4 c) {
    return __builtin_amdgcn_mfma_f32_16x16x32_bf16(
        __builtin_bit_cast(bf16x8, a), __builtin_bit_cast(bf16x8, b), c, 0, 0, 0);
}

// ---- Q element for flat slot index e (= n*160 + k) ----
DEV float q_elem(const float* __restrict__ W, int e) {
    const int n = e / 160;
    const int k = e - n * 160;
    const int s = k >> 5, q = (k >> 3) & 3, j = k & 7;
    const int c = 8 * s + j;
    float qv = 0.f;
    if (c < 36) {
        const int a = (c < 32) ? (c & 3) : (c - 32);
        const int b = (c < 32) ? ((c & 3) + (c >> 2)) : (c - 32 + 8);
        const float w = (c < 32) ? 1.0f : 0.5f;
        const int I = (a + 4 * q) & 15, J = (b + 4 * q) & 15;
        qv = (I == J) ? W[n * 256 + I * 16 + I]
                      : w * (W[n * 256 + I * 16 + J] + W[n * 256 + J * 16 + I]);
    }
    return qv;
}

__global__ __launch_bounds__(256, 8)   // R4: 8 waves/EU target (was 4) -> 32 waves/CU
void bilinear16_kernel(const float* __restrict__ x, const float* __restrict__ W,
                       float* __restrict__ out, int ntiles) {
    // ---- per-block setup: Qt[n][k] bf16, k-slot -> rotated pair, weight-adjusted ----
    __shared__ __align__(16) short Qt[16][160];
    const int tid = threadIdx.x;
    for (int e = tid; e < 16 * 160; e += 256) {
        __hip_bfloat16 h = __float2bfloat16(q_elem(W, e));
        Qt[0][e] = *reinterpret_cast<short*>(&h);
    }
    __syncthreads();

    const int lane = tid & 63;
    const int n    = lane & 15;   // A row m / B col n / C col
    const int q    = lane >> 4;   // quad -> data rotation only, never a branch

    // B-frags in registers for the whole loop (20 VGPRs).
    const short8 b0 = *reinterpret_cast<const short8*>(&Qt[n][0 * 32 + q * 8]);
    const short8 b1 = *reinterpret_cast<const short8*>(&Qt[n][1 * 32 + q * 8]);
    const short8 b2 = *reinterpret_cast<const short8*>(&Qt[n][2 * 32 + q * 8]);
    const short8 b3 = *reinterpret_cast<const short8*>(&Qt[n][3 * 32 + q * 8]);
    const short8 b4 = *reinterpret_cast<const short8*>(&Qt[n][4 * 32 + q * 8]);

    const int waveId = blockIdx.x * 4 + (tid >> 6);
    const int nwaves = gridDim.x * 4;

    for (int t = waveId; t < ntiles; t += nwaves) {
        // Rotated row load: rotated chunk u = raw chunk (u+q)&3; chunks 0..2 suffice.
        // Each load inst's 64 lane addresses tile the full 1KB x-tile (coalesced).
        const float4* xr = reinterpret_cast<const float4*>(x + (size_t)(t * 16 + n) * 16);
        const float4 c0 = xr[q];
        const float4 c1 = xr[(q + 1) & 3];
        const float4 c2 = xr[(q + 2) & 3];
        const float xv[12] = {c0.x, c0.y, c0.z, c0.w,
                              c1.x, c1.y, c1.z, c1.w,
                              c2.x, c2.y, c2.z, c2.w};

        floatx4 acc = {0.f, 0.f, 0.f, 0.f};
        acc = mfma_bf16(make_afrag<0>(xv), b0, acc);
        acc = mfma_bf16(make_afrag<1>(xv), b1, acc);
        acc = mfma_bf16(make_afrag<2>(xv), b2, acc);
        acc = mfma_bf16(make_afrag<3>(xv), b3, acc);
        acc = mfma_bf16(make_afrag<4>(xv), b4, acc);

        // C/D layout: col = lane&15, row = quad*4 + reg  [m89-verified]
        float* ob = out + (size_t)t * 256 + q * 64 + n;
        ob[0]  = acc[0];
        ob[16] = acc[1];
        ob[32] = acc[2];
        ob[48] = acc[3];
    }
}

extern "C" void kernel_launch(void* const* d_in, const int* in_sizes, int n_in,
                              void* d_out, int out_size, void* d_ws, size_t ws_size,
                              hipStream_t stream) {
    const float* x = (const float*)d_in[0];
    const float* W = (const float*)d_in[1];
    float* out = (float*)d_out;
    const int Bn = in_sizes[0] / 16;   // 1048576
    const int ntiles = Bn >> 4;        // 65536
    // 2048 blocks x 4 waves = 8192 waves = 32/CU if (256,8) occupancy is achieved.
    bilinear16_kernel<<<2048, 256, 0, stream>>>(x, W, out, ntiles);
}

// Round 5
// 122.626 us; speedup vs baseline: 1.0391x; 1.0312x over previous
//
#include <hip/hip_runtime.h>
#include <hip/hip_bf16.h>

// out[b,k] = sum_{i,j} x[b,i] * W[k,i,j] * x[b,j]
// GEMM P (B x 160 XOR-classed pair-products) @ Q (160 x 16),
// 5 x mfma_f32_16x16x32_bf16 per 16-row tile.
//
// R5: XOR class algebra. K-slot k = 32s + 8q + j holds, at lane quad q, the
// product x[a]*x[b] with (a,b) = (alpha_c ^ 4q, beta_c ^ 4q), c = 8s+j.
// Class table (c = 0..39), d = a^b:
//   c<24 : d with low2(d)!=0 (12 d's x 2 reps), weight 1   (each pair once)
//   c<36 : d in {4,8,12}     (3 d's x 4 reps),  weight 1/2 (each pair twice)
//   else : d = 0 diagonal    (4 reps),          weight 1   (W[ii], once)
// Coverage verified by orbit enumeration: all 120 off-diag pairs net weight 1,
// all 16 diagonals once. alpha,beta <= 11 (chunks 0..2 only).
//
// Memory structure (the R5 point — R2..R4 stuck at ~43us on VMEM scatter):
//   load : ONE global_load_dwordx4 per tile (lane (n,q) loads chunk q of row n;
//          wave covers the 1KB tile exactly once). Chunks q^1, q^2 arrive via
//          __shfl_xor(.,16)/(.,32)  (lane id = q*16+n -> partners lane^16/^32).
//   store: ONE global_store_dwordx4 per tile after a wave-internal LDS
//          transpose (16 rows x 20-dword padded stride; no barrier needed —
//          same-wave DS ops are ordered, lgkmcnt enforced by compiler).

typedef __attribute__((ext_vector_type(8)))  short  short8;
typedef __attribute__((ext_vector_type(8)))  __bf16 bf16x8;
typedef __attribute__((ext_vector_type(4)))  float  floatx4;

#define DEV static __device__ __forceinline__

// ---- XOR class table ----
constexpr int cA(int c) {            // alpha
    if (c < 24) { const int dIdx = c >> 1, v = c & 1;
        const int hi = dIdx / 3, lo = dIdx % 3 + 1;
        const int base = (hi == 3) ? 1 : 0;
        const int l = v ? ((lo == 1) ? 2 : 1) : 0;
        return base * 4 + l; }
    if (c < 36) { const int g = c - 24, hi = g / 4 + 1, l = g & 3;
        const int base = (hi == 3) ? 1 : 0;
        return base * 4 + l; }
    return c - 36;
}
constexpr int cDd(int c) {           // d = alpha ^ beta
    if (c < 24) { const int dIdx = c >> 1;
        return (dIdx / 3) * 4 + (dIdx % 3 + 1); }
    if (c < 36) { return ((c - 24) / 4 + 1) * 4; }
    return 0;
}
constexpr int   cB(int c) { return cA(c) ^ cDd(c); }
constexpr float cW(int c) { return (c >= 24 && c < 36) ? 0.5f : 1.0f; }

template <int C>
DEV float pval(const float* xv) {    // xv indexed directly by value id (<=11)
    return xv[cA(C)] * xv[cB(C)];
}

template <int S>   // frag S covers classes c = 8S .. 8S+7
DEV short8 make_afrag(const float* xv) {
    union { short8 s; __hip_bfloat162 h[4]; } u;
    u.h[0] = __float22bfloat162_rn(make_float2(pval<8 * S + 0>(xv), pval<8 * S + 1>(xv)));
    u.h[1] = __float22bfloat162_rn(make_float2(pval<8 * S + 2>(xv), pval<8 * S + 3>(xv)));
    u.h[2] = __float22bfloat162_rn(make_float2(pval<8 * S + 4>(xv), pval<8 * S + 5>(xv)));
    u.h[3] = __float22bfloat162_rn(make_float2(pval<8 * S + 6>(xv), pval<8 * S + 7>(xv)));
    return u.s;
}

DEV floatx4 mfma_bf16(short8 a, short8 b, floatx4 c) {
    return __builtin_amdgcn_mfma_f32_16x16x32_bf16(
        __builtin_bit_cast(bf16x8, a), __builtin_bit_cast(bf16x8, b), c, 0, 0, 0);
}

// ---- Q element for flat slot e = n*160 + k,  k = 32s + 8q + j ----
DEV float q_elem(const float* __restrict__ W, int e) {
    const int n = e / 160;
    const int k = e - n * 160;
    const int s = k >> 5, q = (k >> 3) & 3, j = k & 7;
    const int c = 8 * s + j;
    const int I = cA(c) ^ (q << 2);
    const int J = cB(c) ^ (q << 2);
    return (I == J) ? W[n * 256 + I * 16 + I]
                    : cW(c) * (W[n * 256 + I * 16 + J] + W[n * 256 + J * 16 + I]);
}

__global__ __launch_bounds__(256, 8)
void bilinear16_kernel(const float* __restrict__ x, const float* __restrict__ W,
                       float* __restrict__ out, int ntiles) {
    __shared__ __align__(16) short Qt[16][160];   // 5120 B
    __shared__ __align__(16) float Tb[4][320];    // 4 waves x (16 rows x 20 dw) = 5120 B

    const int tid = threadIdx.x;
    for (int e = tid; e < 16 * 160; e += 256) {
        __hip_bfloat16 h = __float2bfloat16(q_elem(W, e));
        Qt[0][e] = *reinterpret_cast<short*>(&h);
    }
    __syncthreads();

    const int lane = tid & 63;
    const int n    = lane & 15;   // MFMA A-row / C col (fixed by HW layout)
    const int q    = lane >> 4;   // MFMA k-group quad
    float* const tb = Tb[tid >> 6];

    // B-frags (20 VGPRs), resident across the loop.
    const short8 b0 = *reinterpret_cast<const short8*>(&Qt[n][0 * 32 + q * 8]);
    const short8 b1 = *reinterpret_cast<const short8*>(&Qt[n][1 * 32 + q * 8]);
    const short8 b2 = *reinterpret_cast<const short8*>(&Qt[n][2 * 32 + q * 8]);
    const short8 b3 = *reinterpret_cast<const short8*>(&Qt[n][3 * 32 + q * 8]);
    const short8 b4 = *reinterpret_cast<const short8*>(&Qt[n][4 * 32 + q * 8]);

    const int waveId = blockIdx.x * 4 + (tid >> 6);
    const int nwaves = gridDim.x * 4;

    for (int t = waveId; t < ntiles; t += nwaves) {
        // ONE coalesced load: lane (n,q) <- chunk q of row n (tile read exactly once).
        const float4 own = *reinterpret_cast<const float4*>(
            x + (size_t)t * 256 + n * 16 + q * 4);
        float4 s1, s2;                 // chunk q^1 from lane^16, chunk q^2 from lane^32
        s1.x = __shfl_xor(own.x, 16); s1.y = __shfl_xor(own.y, 16);
        s1.z = __shfl_xor(own.z, 16); s1.w = __shfl_xor(own.w, 16);
        s2.x = __shfl_xor(own.x, 32); s2.y = __shfl_xor(own.y, 32);
        s2.z = __shfl_xor(own.z, 32); s2.w = __shfl_xor(own.w, 32);
        // xv[v] = x value with id v for this lane's quad frame:
        // value i = alpha^4q lives in raw chunk chunk(alpha)^q = local slot chunk(alpha).
        const float xv[12] = {own.x, own.y, own.z, own.w,
                              s1.x,  s1.y,  s1.z,  s1.w,
                              s2.x,  s2.y,  s2.z,  s2.w};

        floatx4 acc = {0.f, 0.f, 0.f, 0.f};
        acc = mfma_bf16(make_afrag<0>(xv), b0, acc);
        acc = mfma_bf16(make_afrag<1>(xv), b1, acc);
        acc = mfma_bf16(make_afrag<2>(xv), b2, acc);
        acc = mfma_bf16(make_afrag<3>(xv), b3, acc);
        acc = mfma_bf16(make_afrag<4>(xv), b4, acc);

        // C/D layout: col = lane&15, row = q*4 + reg  [m89-verified].
        // Wave-internal LDS transpose -> lane-linear float4 store.
        tb[(q * 4 + 0) * 20 + n] = acc[0];
        tb[(q * 4 + 1) * 20 + n] = acc[1];
        tb[(q * 4 + 2) * 20 + n] = acc[2];
        tb[(q * 4 + 3) * 20 + n] = acc[3];
        const float4 o = *reinterpret_cast<const float4*>(
            &tb[(lane >> 2) * 20 + (lane & 3) * 4]);
        *reinterpret_cast<float4*>(out + (size_t)t * 256 + lane * 4) = o;
    }
}

extern "C" void kernel_launch(void* const* d_in, const int* in_sizes, int n_in,
                              void* d_out, int out_size, void* d_ws, size_t ws_size,
                              hipStream_t stream) {
    const float* x = (const float*)d_in[0];
    const float* W = (const float*)d_in[1];
    float* out = (float*)d_out;
    const int Bn = in_sizes[0] / 16;   // 1048576
    const int ntiles = Bn >> 4;        // 65536
    // 2048 blocks x 4 waves = 8192 waves; 8 tiles/wave exactly.
    bilinear16_kernel<<<2048, 256, 0, stream>>>(x, W, out, ntiles);
}